// Round 2
// baseline (2319.686 us; speedup 1.0000x reference)
//
#include <hip/hip_runtime.h>

#define B_DIM 4
#define C_DIM 512
#define N_DIM 4096
#define C8_DIM 64
#define NS_F 4096.0f

// ---------------------------------------------------------------------------
// proj: out[n][o] = sum_c x[b][c][n] * W[o][c] + bias[o]
// for W in {Wq (ot==0), Wk (ot==1), Wv (ot>=2)} -> qT/kT/vT
// grid (10 o-tiles, 64 n-tiles, 4 b), block 256. Tiles 64n x 64o, BK=32.
// ---------------------------------------------------------------------------
__global__ __launch_bounds__(256) void proj_kernel(
    const float* __restrict__ x,
    const float* __restrict__ Wq, const float* __restrict__ bq,
    const float* __restrict__ Wk, const float* __restrict__ bk,
    const float* __restrict__ Wv, const float* __restrict__ bv,
    float* __restrict__ qT, float* __restrict__ kT, float* __restrict__ vT)
{
    const int b  = blockIdx.z;
    const int n0 = blockIdx.y * 64;
    const int ot = blockIdx.x;

    const float* W; const float* bias; float* out; int ldo; int o0;
    if (ot == 0)      { W = Wq; bias = bq; out = qT + (size_t)b*N_DIM*64;  ldo = 64;  o0 = 0; }
    else if (ot == 1) { W = Wk; bias = bk; out = kT + (size_t)b*N_DIM*64;  ldo = 64;  o0 = 0; }
    else              { W = Wv; bias = bv; out = vT + (size_t)b*N_DIM*512; ldo = 512; o0 = (ot-2)*64; }

    __shared__ float xs[32][68];   // [c][n]  (+4 pad: conflict-free column reads)
    __shared__ float wt[32][68];   // [c][o]

    const int tid = threadIdx.x;
    const int tn = tid & 15;   // n-frag group (4 rows)
    const int to = tid >> 4;   // o-frag group (4 cols)

    float acc[4][4] = {};

    const float* xb = x + (size_t)b*C_DIM*N_DIM + n0;

    for (int c0 = 0; c0 < C_DIM; c0 += 32) {
        // stage x tile [32 c][64 n] (coalesced along n)
        {
            const int r = tid >> 4;       // 0..15
            const int l = tid & 15;       // 0..15
            #pragma unroll
            for (int rr = 0; rr < 32; rr += 16) {
                float4 v = *(const float4*)(xb + (size_t)(c0 + r + rr)*N_DIM + l*4);
                *(float4*)&xs[r + rr][l*4] = v;
            }
        }
        // stage W tile transposed [32 c][64 o] (coalesced along c)
        {
            const int oo = tid >> 2;          // 0..63
            const int cs = (tid & 3) * 8;     // 0,8,16,24
            const float* wr = W + (size_t)(o0 + oo)*C_DIM + c0 + cs;
            #pragma unroll
            for (int q4 = 0; q4 < 2; ++q4) {
                float4 v = *(const float4*)(wr + q4*4);
                wt[cs + q4*4 + 0][oo] = v.x;
                wt[cs + q4*4 + 1][oo] = v.y;
                wt[cs + q4*4 + 2][oo] = v.z;
                wt[cs + q4*4 + 3][oo] = v.w;
            }
        }
        __syncthreads();
        #pragma unroll
        for (int kk = 0; kk < 32; ++kk) {
            float4 a  = *(const float4*)&xs[kk][tn*4];
            float4 w4 = *(const float4*)&wt[kk][to*4];
            acc[0][0] = fmaf(a.x, w4.x, acc[0][0]);
            acc[0][1] = fmaf(a.x, w4.y, acc[0][1]);
            acc[0][2] = fmaf(a.x, w4.z, acc[0][2]);
            acc[0][3] = fmaf(a.x, w4.w, acc[0][3]);
            acc[1][0] = fmaf(a.y, w4.x, acc[1][0]);
            acc[1][1] = fmaf(a.y, w4.y, acc[1][1]);
            acc[1][2] = fmaf(a.y, w4.z, acc[1][2]);
            acc[1][3] = fmaf(a.y, w4.w, acc[1][3]);
            acc[2][0] = fmaf(a.z, w4.x, acc[2][0]);
            acc[2][1] = fmaf(a.z, w4.y, acc[2][1]);
            acc[2][2] = fmaf(a.z, w4.z, acc[2][2]);
            acc[2][3] = fmaf(a.z, w4.w, acc[2][3]);
            acc[3][0] = fmaf(a.w, w4.x, acc[3][0]);
            acc[3][1] = fmaf(a.w, w4.y, acc[3][1]);
            acc[3][2] = fmaf(a.w, w4.z, acc[3][2]);
            acc[3][3] = fmaf(a.w, w4.w, acc[3][3]);
        }
        __syncthreads();
    }

    const float4 b4 = *(const float4*)(bias + o0 + to*4);
    #pragma unroll
    for (int i = 0; i < 4; ++i) {
        const int n = tn*4 + i;
        float4 r;
        r.x = acc[i][0] + b4.x;
        r.y = acc[i][1] + b4.y;
        r.z = acc[i][2] + b4.z;
        r.w = acc[i][3] + b4.w;
        *(float4*)(out + (size_t)(n0 + n)*ldo + o0 + to*4) = r;
    }
}

// ---------------------------------------------------------------------------
// row0: corr[b] = NS * softmax(q0 . k[:,n])[style_idx[b]]
// ---------------------------------------------------------------------------
__global__ __launch_bounds__(256) void row0_kernel(
    const float* __restrict__ qT, const float* __restrict__ kT,
    const int* __restrict__ sidx, float* __restrict__ corr)
{
    const int b = blockIdx.x;
    const int tid = threadIdx.x;
    __shared__ float q0[64];
    __shared__ float lg[N_DIM];
    __shared__ float red[256];
    if (tid < 16) {
        float4 v = ((const float4*)(qT + (size_t)b*N_DIM*64))[tid];
        *(float4*)&q0[tid*4] = v;
    }
    __syncthreads();
    float mx = -3.0e38f;
    for (int n = tid; n < N_DIM; n += 256) {
        const float* kr = kT + ((size_t)b*N_DIM + n)*64;
        float acc = 0.f;
        #pragma unroll
        for (int o = 0; o < 64; o += 4) {
            float4 kv = *(const float4*)(kr + o);
            acc = fmaf(q0[o+0], kv.x, acc);
            acc = fmaf(q0[o+1], kv.y, acc);
            acc = fmaf(q0[o+2], kv.z, acc);
            acc = fmaf(q0[o+3], kv.w, acc);
        }
        lg[n] = acc;
        mx = fmaxf(mx, acc);
    }
    red[tid] = mx; __syncthreads();
    for (int st = 128; st >= 1; st >>= 1) {
        if (tid < st) red[tid] = fmaxf(red[tid], red[tid + st]);
        __syncthreads();
    }
    mx = red[0]; __syncthreads();
    float sm = 0.f;
    for (int n = tid; n < N_DIM; n += 256) sm += __expf(lg[n] - mx);
    red[tid] = sm; __syncthreads();
    for (int st = 128; st >= 1; st >>= 1) {
        if (tid < st) red[tid] += red[tid + st];
        __syncthreads();
    }
    if (tid == 0) {
        corr[b] = NS_F * __expf(lg[sidx[b]] - mx) / red[0];
    }
}

// ---------------------------------------------------------------------------
// flash: per (b, 64-row m-tile): online softmax over 64-wide key tiles,
// O[m][c] = sum_n P[m][n] * vT[n][c], un-normalized until the final divide.
// 512 threads: thread = (mg = tid>>5 -> 4 m rows, nt = tid&31).
// P lives in registers, broadcast to PV via __shfl(width 32).
// LDS: Qt 16K + Kt 16K + Vc 32K = 64 KB -> 2 blocks/CU.
// Barrier audit: Kt is only read in QK^T, which all threads finish before
// chunk 0's first __syncthreads; next tile's Kt writes happen after chunk 3's
// compute, which touches only Vc/registers -> no Kt WAR hazard.
// ---------------------------------------------------------------------------
__global__ __launch_bounds__(512) void flash_kernel(
    const float* __restrict__ qT, const float* __restrict__ kT,
    const float* __restrict__ vT, float* __restrict__ Of)
{
    const int b  = blockIdx.y;
    const int m0 = blockIdx.x * 64;
    const int tid = threadIdx.x;
    const int mg = tid >> 5;   // 0..15
    const int nt = tid & 31;   // 0..31

    __shared__ float Qt[64][64];   // [o][m]
    __shared__ float Kt[64][64];   // [o][n]
    __shared__ float Vc[64][128];  // [n][c-chunk]

    // stage Q transposed
    {
        const int m  = tid >> 3;          // 0..63
        const int os = (tid & 7) * 8;     // 0..56
        const float* qr = qT + ((size_t)b*N_DIM + m0 + m)*64 + os;
        float4 v0 = *(const float4*)qr;
        float4 v1 = *(const float4*)(qr + 4);
        Qt[os+0][m] = v0.x; Qt[os+1][m] = v0.y; Qt[os+2][m] = v0.z; Qt[os+3][m] = v0.w;
        Qt[os+4][m] = v1.x; Qt[os+5][m] = v1.y; Qt[os+6][m] = v1.z; Qt[os+7][m] = v1.w;
    }

    float m_run[4], l_run[4];
    float o_acc[4][16];
    #pragma unroll
    for (int i = 0; i < 4; ++i) {
        m_run[i] = -3.0e38f; l_run[i] = 0.f;
        #pragma unroll
        for (int j = 0; j < 16; ++j) o_acc[i][j] = 0.f;
    }

    __syncthreads();

    #pragma unroll 1
    for (int n0 = 0; n0 < N_DIM; n0 += 64) {
        // stage K transposed [o][n]
        {
            const int n  = tid >> 3;
            const int os = (tid & 7) * 8;
            const float* kr = kT + ((size_t)b*N_DIM + n0 + n)*64 + os;
            float4 v0 = *(const float4*)kr;
            float4 v1 = *(const float4*)(kr + 4);
            Kt[os+0][n] = v0.x; Kt[os+1][n] = v0.y; Kt[os+2][n] = v0.z; Kt[os+3][n] = v0.w;
            Kt[os+4][n] = v1.x; Kt[os+5][n] = v1.y; Kt[os+6][n] = v1.z; Kt[os+7][n] = v1.w;
        }
        __syncthreads();

        // QK^T: s[i][k] for m = m0+mg*4+i, key n0+nt*2+k
        float s[4][2] = {{0.f,0.f},{0.f,0.f},{0.f,0.f},{0.f,0.f}};
        #pragma unroll 16
        for (int o = 0; o < 64; ++o) {
            float4 qv = *(const float4*)&Qt[o][mg*4];   // broadcast within mg group
            float2 kv = *(const float2*)&Kt[o][nt*2];
            s[0][0] = fmaf(qv.x, kv.x, s[0][0]); s[0][1] = fmaf(qv.x, kv.y, s[0][1]);
            s[1][0] = fmaf(qv.y, kv.x, s[1][0]); s[1][1] = fmaf(qv.y, kv.y, s[1][1]);
            s[2][0] = fmaf(qv.z, kv.x, s[2][0]); s[2][1] = fmaf(qv.z, kv.y, s[2][1]);
            s[3][0] = fmaf(qv.w, kv.x, s[3][0]); s[3][1] = fmaf(qv.w, kv.y, s[3][1]);
        }

        // online softmax (row reduce across the 32 nt lanes)
        float p[4][2];
        #pragma unroll
        for (int i = 0; i < 4; ++i) {
            float pm = fmaxf(s[i][0], s[i][1]);
            #pragma unroll
            for (int off = 16; off >= 1; off >>= 1)
                pm = fmaxf(pm, __shfl_xor(pm, off, 32));
            const float nm = fmaxf(m_run[i], pm);
            const float sc = __expf(m_run[i] - nm);
            p[i][0] = __expf(s[i][0] - nm);
            p[i][1] = __expf(s[i][1] - nm);
            float ps = p[i][0] + p[i][1];
            #pragma unroll
            for (int off = 16; off >= 1; off >>= 1)
                ps += __shfl_xor(ps, off, 32);
            l_run[i] = l_run[i]*sc + ps;
            m_run[i] = nm;
            #pragma unroll
            for (int j = 0; j < 16; ++j) o_acc[i][j] *= sc;
        }

        // PV: 4 chunks of 128 c staged through LDS
        #pragma unroll
        for (int ch = 0; ch < 4; ++ch) {
            const int ch4 = ch * 4;
            __syncthreads();   // prev chunk (or QK^T phase) consumers done
            {
                #pragma unroll
                for (int p4 = 0; p4 < 4; ++p4) {
                    const int flat = p4*2048 + tid*4;
                    const int n  = flat >> 7;
                    const int cc = flat & 127;
                    float4 v = *(const float4*)(vT + ((size_t)b*N_DIM + n0 + n)*512 + ch*128 + cc);
                    *(float4*)&Vc[n][cc] = v;
                }
            }
            __syncthreads();
            #pragma unroll 8
            for (int n2 = 0; n2 < 32; ++n2) {
                float pa[4], pb[4];
                #pragma unroll
                for (int i = 0; i < 4; ++i) {
                    pa[i] = __shfl(p[i][0], n2, 32);
                    pb[i] = __shfl(p[i][1], n2, 32);
                }
                float4 va = *(const float4*)&Vc[2*n2  ][nt*4];
                float4 vb = *(const float4*)&Vc[2*n2+1][nt*4];
                #pragma unroll
                for (int i = 0; i < 4; ++i) {
                    o_acc[i][ch4+0] = fmaf(pb[i], vb.x, fmaf(pa[i], va.x, o_acc[i][ch4+0]));
                    o_acc[i][ch4+1] = fmaf(pb[i], vb.y, fmaf(pa[i], va.y, o_acc[i][ch4+1]));
                    o_acc[i][ch4+2] = fmaf(pb[i], vb.z, fmaf(pa[i], va.z, o_acc[i][ch4+2]));
                    o_acc[i][ch4+3] = fmaf(pb[i], vb.w, fmaf(pa[i], va.w, o_acc[i][ch4+3]));
                }
            }
        }
    }

    // normalize and store O[m][c]
    #pragma unroll
    for (int i = 0; i < 4; ++i) {
        const float inv = 1.0f / l_run[i];
        float* orow = Of + ((size_t)b*N_DIM + m0 + mg*4 + i)*512;
        #pragma unroll
        for (int ch = 0; ch < 4; ++ch) {
            float4 r;
            r.x = o_acc[i][ch*4+0] * inv;
            r.y = o_acc[i][ch*4+1] * inv;
            r.z = o_acc[i][ch*4+2] * inv;
            r.w = o_acc[i][ch*4+3] * inv;
            *(float4*)(orow + ch*128 + nt*4) = r;
        }
    }
}

// ---------------------------------------------------------------------------
// epilogue: out[b][c][n] = gamma*(NS*O[b][n][c] - (n==0)*corr[b]*vT[b][s][c]) + x[b][c][n]
// transpose via LDS 64x64 tile.
// ---------------------------------------------------------------------------
__global__ __launch_bounds__(256) void epilogue_kernel(
    const float* __restrict__ Of, const float* __restrict__ x,
    const float* __restrict__ vT, const float* __restrict__ corr,
    const float* __restrict__ gamma, const int* __restrict__ sidx,
    float* __restrict__ out)
{
    const int b  = blockIdx.z;
    const int c0 = blockIdx.y * 64;
    const int n0 = blockIdx.x * 64;
    __shared__ float t[64][68];
    const int tid = threadIdx.x;
    {
        const int nr = tid >> 4;          // 0..15
        const int cs = (tid & 15) * 4;
        #pragma unroll
        for (int p4 = 0; p4 < 4; ++p4) {
            const int n = nr + p4*16;
            float4 v = *(const float4*)(Of + ((size_t)b*N_DIM + n0 + n)*512 + c0 + cs);
            *(float4*)&t[n][cs] = v;
        }
    }
    __syncthreads();
    const float g  = gamma[0];
    const int   s  = sidx[b];
    const float cb = corr[b];
    const int cw = tid >> 4;   // 0..15
    const int nl = tid & 15;   // 0..15
    #pragma unroll
    for (int i = 0; i < 4; ++i) {
        const int c = cw*4 + i;
        float4 xv = *(const float4*)(x + ((size_t)b*C_DIM + c0 + c)*N_DIM + n0 + nl*4);
        float4 r;
        r.x = fmaf(g*NS_F, t[nl*4+0][c], xv.x);
        r.y = fmaf(g*NS_F, t[nl*4+1][c], xv.y);
        r.z = fmaf(g*NS_F, t[nl*4+2][c], xv.z);
        r.w = fmaf(g*NS_F, t[nl*4+3][c], xv.w);
        if (n0 == 0 && nl == 0) {
            const float vsv = vT[((size_t)b*N_DIM + s)*512 + c0 + c];
            r.x -= g * cb * vsv;
        }
        *(float4*)(out + ((size_t)b*C_DIM + c0 + c)*N_DIM + n0 + nl*4) = r;
    }
}

// ---------------------------------------------------------------------------
extern "C" void kernel_launch(void* const* d_in, const int* in_sizes, int n_in,
                              void* d_out, int out_size, void* d_ws, size_t ws_size,
                              hipStream_t stream)
{
    const float* x     = (const float*)d_in[0];
    const float* Wq    = (const float*)d_in[1];
    const float* bq    = (const float*)d_in[2];
    const float* Wk    = (const float*)d_in[3];
    const float* bk    = (const float*)d_in[4];
    const float* Wv    = (const float*)d_in[5];
    const float* bv    = (const float*)d_in[6];
    const float* gamma = (const float*)d_in[7];
    const int*   sidx  = (const int*)d_in[8];
    float* out = (float*)d_out;

    // workspace layout (floats): qT 1M | kT 1M | vT 8M | Of 8M | corr 4
    float* ws = (float*)d_ws;
    float* qT   = ws;                                   // B*N*64
    float* kT   = qT + (size_t)B_DIM*N_DIM*64;          // B*N*64
    float* vT   = kT + (size_t)B_DIM*N_DIM*64;          // B*N*512
    float* Of   = vT + (size_t)B_DIM*N_DIM*512;         // B*N*512
    float* corr = Of + (size_t)B_DIM*N_DIM*512;         // B

    proj_kernel<<<dim3(10, 64, B_DIM), 256, 0, stream>>>(x, Wq, bq, Wk, bk, Wv, bv, qT, kT, vT);
    row0_kernel<<<dim3(B_DIM), 256, 0, stream>>>(qT, kT, sidx, corr);
    flash_kernel<<<dim3(N_DIM/64, B_DIM), 512, 0, stream>>>(qT, kT, vT, Of);
    epilogue_kernel<<<dim3(N_DIM/64, C_DIM/64, B_DIM), 256, 0, stream>>>(Of, x, vT, corr, gamma, sidx, out);
}

// Round 3
// 459.862 us; speedup vs baseline: 5.0443x; 5.0443x over previous
//
#include <hip/hip_runtime.h>
#include <hip/hip_bf16.h>

#define B_DIM 4
#define C_DIM 512
#define N_DIM 4096
#define NS_F 4096.0f

typedef __attribute__((ext_vector_type(8))) short bf16x8;   // 8 bf16 = 4 VGPR
typedef __attribute__((ext_vector_type(4))) float f32x4;

__device__ __forceinline__ unsigned short f2bf(float f) {
    union { float f; unsigned int u; } a; a.f = f;
    unsigned int u = a.u;
    return (unsigned short)((u + 0x7fffu + ((u >> 16) & 1u)) >> 16);  // RNE
}
__device__ __forceinline__ float bf2f(unsigned short s) {
    union { unsigned int u; float f; } a; a.u = ((unsigned int)s) << 16;
    return a.f;
}

// ---------------------------------------------------------------------------
// proj: fp32 GEMM (64n x 64o tile, BK=32), bf16 outputs:
//   qB[b][n][o]            (plain)
//   kB[b][n][o ^ ((n&7)<<3)]  (XOR-swizzle baked in for conflict-free LDS reads)
//   vB[b][c][n]            (transposed: PV consumes V as A-operand rows = c)
// ---------------------------------------------------------------------------
__global__ __launch_bounds__(256) void proj_kernel(
    const float* __restrict__ x,
    const float* __restrict__ Wq, const float* __restrict__ bq,
    const float* __restrict__ Wk, const float* __restrict__ bk,
    const float* __restrict__ Wv, const float* __restrict__ bv,
    unsigned short* __restrict__ qB, unsigned short* __restrict__ kB,
    unsigned short* __restrict__ vB)
{
    const int b  = blockIdx.z;
    const int n0 = blockIdx.y * 64;
    const int ot = blockIdx.x;

    const float* W; const float* bias; int o0;
    if (ot == 0)      { W = Wq; bias = bq; o0 = 0; }
    else if (ot == 1) { W = Wk; bias = bk; o0 = 0; }
    else              { W = Wv; bias = bv; o0 = (ot - 2) * 64; }

    __shared__ float xs[32][68];
    __shared__ float wt[32][68];

    const int tid = threadIdx.x;
    const int tn = tid & 15;
    const int to = tid >> 4;

    float acc[4][4] = {};
    const float* xb = x + (size_t)b * C_DIM * N_DIM + n0;

    for (int c0 = 0; c0 < C_DIM; c0 += 32) {
        {
            const int r = tid >> 4;
            const int l = tid & 15;
            #pragma unroll
            for (int rr = 0; rr < 32; rr += 16) {
                float4 v = *(const float4*)(xb + (size_t)(c0 + r + rr) * N_DIM + l * 4);
                *(float4*)&xs[r + rr][l * 4] = v;
            }
        }
        {
            const int oo = tid >> 2;
            const int csq = (tid & 3) * 8;
            const float* wr = W + (size_t)(o0 + oo) * C_DIM + c0 + csq;
            #pragma unroll
            for (int q4 = 0; q4 < 2; ++q4) {
                float4 v = *(const float4*)(wr + q4 * 4);
                wt[csq + q4 * 4 + 0][oo] = v.x;
                wt[csq + q4 * 4 + 1][oo] = v.y;
                wt[csq + q4 * 4 + 2][oo] = v.z;
                wt[csq + q4 * 4 + 3][oo] = v.w;
            }
        }
        __syncthreads();
        #pragma unroll
        for (int kk = 0; kk < 32; ++kk) {
            float4 a  = *(const float4*)&xs[kk][tn * 4];
            float4 w4 = *(const float4*)&wt[kk][to * 4];
            acc[0][0] = fmaf(a.x, w4.x, acc[0][0]); acc[0][1] = fmaf(a.x, w4.y, acc[0][1]);
            acc[0][2] = fmaf(a.x, w4.z, acc[0][2]); acc[0][3] = fmaf(a.x, w4.w, acc[0][3]);
            acc[1][0] = fmaf(a.y, w4.x, acc[1][0]); acc[1][1] = fmaf(a.y, w4.y, acc[1][1]);
            acc[1][2] = fmaf(a.y, w4.z, acc[1][2]); acc[1][3] = fmaf(a.y, w4.w, acc[1][3]);
            acc[2][0] = fmaf(a.z, w4.x, acc[2][0]); acc[2][1] = fmaf(a.z, w4.y, acc[2][1]);
            acc[2][2] = fmaf(a.z, w4.z, acc[2][2]); acc[2][3] = fmaf(a.z, w4.w, acc[2][3]);
            acc[3][0] = fmaf(a.w, w4.x, acc[3][0]); acc[3][1] = fmaf(a.w, w4.y, acc[3][1]);
            acc[3][2] = fmaf(a.w, w4.z, acc[3][2]); acc[3][3] = fmaf(a.w, w4.w, acc[3][3]);
        }
        __syncthreads();
    }

    const float4 b4 = *(const float4*)(bias + o0 + to * 4);
    const float barr[4] = {b4.x, b4.y, b4.z, b4.w};

    if (ot == 0) {
        #pragma unroll
        for (int i = 0; i < 4; ++i) {
            const int n = n0 + tn * 4 + i;
            ushort4 r4;
            r4.x = f2bf(acc[i][0] + barr[0]); r4.y = f2bf(acc[i][1] + barr[1]);
            r4.z = f2bf(acc[i][2] + barr[2]); r4.w = f2bf(acc[i][3] + barr[3]);
            *(ushort4*)(qB + ((size_t)b * N_DIM + n) * 64 + to * 4) = r4;
        }
    } else if (ot == 1) {
        #pragma unroll
        for (int i = 0; i < 4; ++i) {
            const int n = n0 + tn * 4 + i;
            const int col = (to * 4) ^ ((n & 7) << 3);
            ushort4 r4;
            r4.x = f2bf(acc[i][0] + barr[0]); r4.y = f2bf(acc[i][1] + barr[1]);
            r4.z = f2bf(acc[i][2] + barr[2]); r4.w = f2bf(acc[i][3] + barr[3]);
            *(ushort4*)(kB + ((size_t)b * N_DIM + n) * 64 + col) = r4;
        }
    } else {
        #pragma unroll
        for (int j = 0; j < 4; ++j) {
            const int c = o0 + to * 4 + j;
            ushort4 r4;
            r4.x = f2bf(acc[0][j] + barr[j]); r4.y = f2bf(acc[1][j] + barr[j]);
            r4.z = f2bf(acc[2][j] + barr[j]); r4.w = f2bf(acc[3][j] + barr[j]);
            *(ushort4*)(vB + ((size_t)b * C_DIM + c) * N_DIM + n0 + tn * 4) = r4;
        }
    }
}

// ---------------------------------------------------------------------------
// row0: corr[b] = NS * softmax(q0 . k_n)[style_idx[b]]  (bf16 inputs, f32 math
// -> matches flash's MFMA logits up to summation order)
// ---------------------------------------------------------------------------
__global__ __launch_bounds__(256) void row0_kernel(
    const unsigned short* __restrict__ qB,
    const unsigned short* __restrict__ kB,
    const int* __restrict__ sidx, float* __restrict__ corr)
{
    const int b = blockIdx.x;
    const int tid = threadIdx.x;
    __shared__ float q0[64];
    __shared__ float lg[N_DIM];
    __shared__ float red[256];
    if (tid < 64) q0[tid] = bf2f(qB[(size_t)b * N_DIM * 64 + tid]);
    __syncthreads();
    float mx = -3.0e38f;
    for (int n = tid; n < N_DIM; n += 256) {
        const unsigned short* kr = kB + ((size_t)b * N_DIM + n) * 64;
        const int m7 = n & 7;
        float acc = 0.f;
        #pragma unroll
        for (int jc = 0; jc < 8; ++jc) {
            bf16x8 kv = *(const bf16x8*)(kr + jc * 8);
            const int dj = (jc ^ m7) * 8;   // de-swizzle: slot jc holds data chunk jc^m7
            #pragma unroll
            for (int e = 0; e < 8; ++e)
                acc = fmaf(bf2f((unsigned short)kv[e]), q0[dj + e], acc);
        }
        lg[n] = acc;
        mx = fmaxf(mx, acc);
    }
    red[tid] = mx; __syncthreads();
    for (int st = 128; st >= 1; st >>= 1) {
        if (tid < st) red[tid] = fmaxf(red[tid], red[tid + st]);
        __syncthreads();
    }
    mx = red[0]; __syncthreads();
    float sm = 0.f;
    for (int n = tid; n < N_DIM; n += 256) sm += __expf(lg[n] - mx);
    red[tid] = sm; __syncthreads();
    for (int st = 128; st >= 1; st >>= 1) {
        if (tid < st) red[tid] += red[tid + st];
        __syncthreads();
    }
    if (tid == 0) corr[b] = NS_F * __expf(lg[sidx[b]] - mx) / red[0];
}

// ---------------------------------------------------------------------------
// flash (MFMA): grid 512 = {4 b} x {64 m-tiles} x {2 c-halves}, 256 thr.
// XCD map: batch b pinned to XCDs {2b,2b+1} so its V-half stays L2-resident.
// Per block: BM=64 q-rows, c-half = 256 cols (wave w owns 64), KV-tile 64.
// QK^T computed as S^T = mfma(K, Q) -> softmax reduction is lane-local.
// P through XOR-swizzled LDS; V fragments straight from global (L2);
// K double-buffered with register prefetch. Epilogue (x add, gamma*NS,
// style correction) folded in; output written as out[b][c][n] directly.
// ---------------------------------------------------------------------------
__global__ __launch_bounds__(256, 2) void flash_kernel(
    const unsigned short* __restrict__ qB,
    const unsigned short* __restrict__ kB,
    const unsigned short* __restrict__ vB,
    const float* __restrict__ x,
    const float* __restrict__ corr,
    const float* __restrict__ gamma,
    const int* __restrict__ sidx,
    float* __restrict__ out)
{
    const int bid = blockIdx.x;
    const int b   = (bid & 7) >> 1;        // batch -> XCD pair
    const int ch  = bid & 1;               // c-half
    const int mt  = bid >> 3;              // 0..63
    const int m0  = mt * 64;

    const int tid  = threadIdx.x;
    const int w    = tid >> 6;
    const int lane = tid & 63;
    const int lql  = lane & 15;
    const int lk4  = lane >> 4;
    const int swz  = (lql & 7) << 3;       // ushort-index XOR (16B-chunk swizzle)

    __shared__ __align__(16) unsigned short Kl[2][4096]; // [key][d] swizzled
    __shared__ __align__(16) unsigned short Pl[4096];    // [qrow][key] swizzled
    __shared__ float scl[64];
    __shared__ float ll[64];
    __shared__ int   fl[4];

    // Q B-frags (col = qrow = lane&15, k = d)
    const unsigned short* qrow = qB + ((size_t)b * N_DIM + m0 + w * 16 + lql) * 64 + lk4 * 8;
    const bf16x8 qf0 = *(const bf16x8*)(qrow);
    const bf16x8 qf1 = *(const bf16x8*)(qrow + 32);

    f32x4 acc[4][4];   // [cg][qg]
    #pragma unroll
    for (int cg = 0; cg < 4; ++cg)
        #pragma unroll
        for (int qg = 0; qg < 4; ++qg)
            acc[cg][qg] = (f32x4){0.f, 0.f, 0.f, 0.f};

    float m_run = -3.0e38f;
    float l_run = 0.f;

    const unsigned short* kbb = kB + (size_t)b * N_DIM * 64;
    const unsigned short* vbb = vB + (size_t)b * C_DIM * N_DIM;
    const int cs = ch * 256 + w * 64;

    // stage K tile 0 (linear copy; swizzle pre-baked in kB)
    {
        bf16x8 a0 = *(const bf16x8*)(kbb + tid * 16);
        bf16x8 a1 = *(const bf16x8*)(kbb + tid * 16 + 8);
        *(bf16x8*)(&Kl[0][tid * 16]) = a0;
        *(bf16x8*)(&Kl[0][tid * 16 + 8]) = a1;
    }
    __syncthreads();

    int buf = 0;
    for (int t = 0; t < 64; ++t) {
        // prefetch next K tile into registers (consumed after barrier 1)
        const int tn_ = (t + 1) & 63;
        const bf16x8 kn0 = *(const bf16x8*)(kbb + (size_t)tn_ * 4096 + tid * 16);
        const bf16x8 kn1 = *(const bf16x8*)(kbb + (size_t)tn_ * 4096 + tid * 16 + 8);

        // QK^T -> S^T tiles: s[g] rows = keys g*16+lk4*4+r, col = qrow = lql
        f32x4 s[4];
        #pragma unroll
        for (int g = 0; g < 4; ++g) {
            const unsigned short* kr = &Kl[buf][(g * 16 + lql) * 64];
            bf16x8 ka0 = *(const bf16x8*)(kr + ((lk4 * 8) ^ swz));
            bf16x8 ka1 = *(const bf16x8*)(kr + ((lk4 * 8 + 32) ^ swz));
            f32x4 z = (f32x4){0.f, 0.f, 0.f, 0.f};
            z = __builtin_amdgcn_mfma_f32_16x16x32_bf16(ka0, qf0, z, 0, 0, 0);
            z = __builtin_amdgcn_mfma_f32_16x16x32_bf16(ka1, qf1, z, 0, 0, 0);
            s[g] = z;
        }

        // online softmax (16 S values per lane, all same qrow)
        float pmax = s[0][0];
        #pragma unroll
        for (int g = 0; g < 4; ++g)
            #pragma unroll
            for (int r = 0; r < 4; ++r)
                pmax = fmaxf(pmax, s[g][r]);
        pmax = fmaxf(pmax, __shfl_xor(pmax, 16));
        pmax = fmaxf(pmax, __shfl_xor(pmax, 32));

        const int wflag = __any(pmax > m_run + 8.f);   // defer-max THR=8
        float scv = 1.f;
        if (wflag) {
            const float nm = fmaxf(m_run, pmax);
            scv = __expf(m_run - nm);
            m_run = nm;
        }
        float p[4][4];
        float ps = 0.f;
        #pragma unroll
        for (int g = 0; g < 4; ++g)
            #pragma unroll
            for (int r = 0; r < 4; ++r) {
                p[g][r] = __expf(s[g][r] - m_run);
                ps += p[g][r];
            }
        ps += __shfl_xor(ps, 16);
        ps += __shfl_xor(ps, 32);
        l_run = l_run * scv + ps;

        if (lk4 == 0) scl[w * 16 + lql] = scv;
        if (lane == 0) fl[w] = wflag;

        // P -> LDS (bf16, swizzled): row w*16+lql, keys g*16+lk4*4+{0..3}
        {
            const int prow = (w * 16 + lql) * 64;
            #pragma unroll
            for (int g = 0; g < 4; ++g) {
                unsigned int lo = (unsigned int)f2bf(p[g][0]) | ((unsigned int)f2bf(p[g][1]) << 16);
                unsigned int hi = (unsigned int)f2bf(p[g][2]) | ((unsigned int)f2bf(p[g][3]) << 16);
                *(uint2*)(&Pl[prow + ((g * 16 + lk4 * 4) ^ swz)]) = make_uint2(lo, hi);
            }
        }
        __syncthreads();   // P/scl/fl visible; prev-tile PV reads done

        // write prefetched K into the other buffer (read after barrier 2)
        *(bf16x8*)(&Kl[buf ^ 1][tid * 16]) = kn0;
        *(bf16x8*)(&Kl[buf ^ 1][tid * 16 + 8]) = kn1;

        // O rescale (skipped unless some wave bumped its max)
        const int bflag = fl[0] | fl[1] | fl[2] | fl[3];
        if (bflag) {
            float sc4[4];
            #pragma unroll
            for (int qg = 0; qg < 4; ++qg) sc4[qg] = scl[qg * 16 + lql];
            #pragma unroll
            for (int cg = 0; cg < 4; ++cg)
                #pragma unroll
                for (int qg = 0; qg < 4; ++qg) {
                    acc[cg][qg][0] *= sc4[qg];
                    acc[cg][qg][1] *= sc4[qg];
                    acc[cg][qg][2] *= sc4[qg];
                    acc[cg][qg][3] *= sc4[qg];
                }
        }

        // P B-frags (col = qrow, k = key)
        bf16x8 pf[4][2];
        #pragma unroll
        for (int qg = 0; qg < 4; ++qg) {
            const unsigned short* pr = &Pl[(qg * 16 + lql) * 64];
            pf[qg][0] = *(const bf16x8*)(pr + ((lk4 * 8) ^ swz));
            pf[qg][1] = *(const bf16x8*)(pr + ((lk4 * 8 + 32) ^ swz));
        }

        // PV: O^T[c][qrow] += V^T[c][key] * P^T[key][qrow]; V direct from L2
        const int n0 = t * 64;
        const unsigned short* vpb = vbb + (size_t)(cs + lql) * N_DIM + n0 + lk4 * 8;
        #pragma unroll
        for (int cg = 0; cg < 4; ++cg) {
            const unsigned short* vp = vpb + (size_t)cg * 16 * N_DIM;
            bf16x8 va0 = *(const bf16x8*)(vp);
            bf16x8 va1 = *(const bf16x8*)(vp + 32);
            #pragma unroll
            for (int qg = 0; qg < 4; ++qg) {
                acc[cg][qg] = __builtin_amdgcn_mfma_f32_16x16x32_bf16(va0, pf[qg][0], acc[cg][qg], 0, 0, 0);
                acc[cg][qg] = __builtin_amdgcn_mfma_f32_16x16x32_bf16(va1, pf[qg][1], acc[cg][qg], 0, 0, 0);
            }
        }
        __syncthreads();   // PV reads done; K[buf^1] staged
        buf ^= 1;
    }

    // epilogue: out[b][c][n] = gamma*NS*O/l + x - (n==0)*gamma*corr*v[c][s]
    if (lk4 == 0) ll[w * 16 + lql] = l_run;
    __syncthreads();

    const float g0  = gamma[0];
    const float gns = g0 * NS_F;
    float inv4[4];
    #pragma unroll
    for (int qg = 0; qg < 4; ++qg) inv4[qg] = 1.f / ll[qg * 16 + lql];

    const bool corner = (m0 == 0) && (lql == 0);
    float cb = 0.f; int sst = 0;
    if (corner) { cb = corr[b] * g0; sst = sidx[b]; }

    #pragma unroll
    for (int cg = 0; cg < 4; ++cg) {
        #pragma unroll
        for (int r = 0; r < 4; ++r) {
            const int c = cs + cg * 16 + lk4 * 4 + r;
            const size_t rowb = ((size_t)b * C_DIM + c) * N_DIM;
            float vcorr = 0.f;
            if (corner) vcorr = cb * bf2f(vbb[(size_t)c * N_DIM + sst]);
            #pragma unroll
            for (int qg = 0; qg < 4; ++qg) {
                const int mg = m0 + qg * 16 + lql;
                float val = fmaf(gns * inv4[qg], acc[cg][qg][r], x[rowb + mg]);
                if (qg == 0 && corner) val -= vcorr;
                out[rowb + mg] = val;
            }
        }
    }
}

// ---------------------------------------------------------------------------
extern "C" void kernel_launch(void* const* d_in, const int* in_sizes, int n_in,
                              void* d_out, int out_size, void* d_ws, size_t ws_size,
                              hipStream_t stream)
{
    const float* x     = (const float*)d_in[0];
    const float* Wq    = (const float*)d_in[1];
    const float* bq    = (const float*)d_in[2];
    const float* Wk    = (const float*)d_in[3];
    const float* bk    = (const float*)d_in[4];
    const float* Wv    = (const float*)d_in[5];
    const float* bv    = (const float*)d_in[6];
    const float* gamma = (const float*)d_in[7];
    const int*   sidx  = (const int*)d_in[8];
    float* out = (float*)d_out;

    // ws: qB 2MB | kB 2MB | vB 16MB | corr
    unsigned short* qB = (unsigned short*)d_ws;
    unsigned short* kB = qB + (size_t)B_DIM * N_DIM * 64;
    unsigned short* vB = kB + (size_t)B_DIM * N_DIM * 64;
    float* corr = (float*)(vB + (size_t)B_DIM * C_DIM * N_DIM);

    proj_kernel<<<dim3(10, 64, B_DIM), 256, 0, stream>>>(x, Wq, bq, Wk, bk, Wv, bv, qB, kB, vB);
    row0_kernel<<<dim3(B_DIM), 256, 0, stream>>>(qB, kB, sidx, corr);
    flash_kernel<<<dim3(512), 256, 0, stream>>>(qB, kB, vB, x, corr, gamma, sidx, out);
}

// Round 7
// 350.671 us; speedup vs baseline: 6.6150x; 1.3114x over previous
//
#include <hip/hip_runtime.h>

#define B_DIM 4
#define C_DIM 512
#define N_DIM 4096
#define NS_F 4096.0f

typedef __attribute__((ext_vector_type(8))) short bf16x8;   // 8 bf16 = 4 VGPR
typedef __attribute__((ext_vector_type(4))) float f32x4;

__device__ __forceinline__ unsigned short f2bf(float f) {
    union { float f; unsigned int u; } a; a.f = f;
    unsigned int u = a.u;
    return (unsigned short)((u + 0x7fffu + ((u >> 16) & 1u)) >> 16);  // RNE
}
__device__ __forceinline__ float bf2f(unsigned short s) {
    union { unsigned int u; float f; } a; a.u = ((unsigned int)s) << 16;
    return a.f;
}

// ---------------------------------------------------------------------------
// wconv: W{q,k,v} fp32 -> bf16 concat [Wq | Wk | Wv] (same [o][c] layout)
// ---------------------------------------------------------------------------
__global__ __launch_bounds__(256) void wconv_kernel(
    const float* __restrict__ Wq, const float* __restrict__ Wk,
    const float* __restrict__ Wv, unsigned short* __restrict__ Wb)
{
    const int gid = blockIdx.x * 256 + threadIdx.x;   // 0..81919 float4 chunks
    const int flat = gid * 4;
    const float* src;
    if (flat < 32768)      src = Wq + flat;
    else if (flat < 65536) src = Wk + (flat - 32768);
    else                   src = Wv + (flat - 65536);
    float4 v = *(const float4*)src;
    ushort4 r;
    r.x = f2bf(v.x); r.y = f2bf(v.y); r.z = f2bf(v.z); r.w = f2bf(v.w);
    *(ushort4*)(Wb + flat) = r;
}

// ---------------------------------------------------------------------------
// xt: x[b][c][n] fp32 -> xT[b][n][c] bf16.  64x64 tile via LDS [64][65] fp32
// (both write and read phases are 2-way-bank-max = free).
// ---------------------------------------------------------------------------
__global__ __launch_bounds__(256) void xt_kernel(
    const float* __restrict__ x, unsigned short* __restrict__ xT)
{
    const int b  = blockIdx.z;
    const int c0 = blockIdx.y * 64;
    const int n0 = blockIdx.x * 64;
    __shared__ float T[64][65];
    const int t   = threadIdx.x;
    const int l16 = t & 15;    // n-group (4 n)
    const int cr  = t >> 4;    // 0..15

    #pragma unroll
    for (int j = 0; j < 4; ++j) {
        const int c = cr + j * 16;
        float4 v = *(const float4*)(x + ((size_t)(b * C_DIM + c0 + c)) * N_DIM + n0 + l16 * 4);
        T[l16 * 4 + 0][c] = v.x;
        T[l16 * 4 + 1][c] = v.y;
        T[l16 * 4 + 2][c] = v.z;
        T[l16 * 4 + 3][c] = v.w;
    }
    __syncthreads();
    #pragma unroll
    for (int j = 0; j < 2; ++j) {
        const int chunk = t + j * 256;      // 0..511
        const int n  = chunk >> 3;
        const int c8 = (chunk & 7) * 8;
        bf16x8 r;
        #pragma unroll
        for (int e = 0; e < 8; ++e) r[e] = (short)f2bf(T[n][c8 + e]);
        *(bf16x8*)(xT + ((size_t)b * N_DIM + n0 + n) * 512 + c0 + c8) = r;
    }
}

// ---------------------------------------------------------------------------
// proj (MFMA, zero LDS): grid (10 ot, 64 nt, 4 b), 256 thr = 4 waves.
//   ot 0: qB[n][o]  = xT . Wq^T + bq        D[n-row][o-col], A=xT, B=Wq
//   ot 1: kB[n][o^] same with XOR-swizzled o column (flash LDS layout)
//   ot 2..9: vB[c][n] = Wv . x + bv         D[c-row][n-col], A=Wv, B=xT
// All A/B fragments are direct 16B global loads (xT and Wb are k-contiguous).
// ---------------------------------------------------------------------------
__global__ __launch_bounds__(256, 4) void proj_kernel(
    const unsigned short* __restrict__ xT, const unsigned short* __restrict__ Wb,
    const float* __restrict__ bq, const float* __restrict__ bk,
    const float* __restrict__ bv,
    unsigned short* __restrict__ qB, unsigned short* __restrict__ kB,
    unsigned short* __restrict__ vB)
{
    const int ot = blockIdx.x;
    const int n0 = blockIdx.y * 64;
    const int b  = blockIdx.z;
    const int tid  = threadIdx.x;
    const int w    = tid >> 6;
    const int lane = tid & 63;
    const int lql  = lane & 15;
    const int lk4  = lane >> 4;

    f32x4 acc[4];
    #pragma unroll
    for (int og = 0; og < 4; ++og) acc[og] = (f32x4){0.f, 0.f, 0.f, 0.f};

    if (ot < 2) {
        const unsigned short* Wp = Wb + ot * 32768;
        const unsigned short* xa = xT + ((size_t)b * N_DIM + n0 + w * 16 + lql) * 512 + lk4 * 8;
        for (int c0 = 0; c0 < 512; c0 += 32) {
            bf16x8 a = *(const bf16x8*)(xa + c0);
            #pragma unroll
            for (int og = 0; og < 4; ++og) {
                bf16x8 wf = *(const bf16x8*)(Wp + (size_t)(og * 16 + lql) * 512 + c0 + lk4 * 8);
                acc[og] = __builtin_amdgcn_mfma_f32_16x16x32_bf16(a, wf, acc[og], 0, 0, 0);
            }
        }
        const float* bias = (ot == 0) ? bq : bk;
        #pragma unroll
        for (int og = 0; og < 4; ++og) {
            const float bb = bias[og * 16 + lql];
            #pragma unroll
            for (int r = 0; r < 4; ++r) {
                const int n = n0 + w * 16 + lk4 * 4 + r;
                const unsigned short val = f2bf(acc[og][r] + bb);
                if (ot == 0) {
                    qB[((size_t)b * N_DIM + n) * 64 + og * 16 + lql] = val;
                } else {
                    const int o = og * 16 + lql;
                    kB[((size_t)b * N_DIM + n) * 64 + (o ^ ((n & 7) << 3))] = val;
                }
            }
        }
    } else {
        const int cb0 = (ot - 2) * 64;
        const unsigned short* wa = Wb + 65536 + (size_t)(cb0 + w * 16 + lql) * 512 + lk4 * 8;
        const unsigned short* xb = xT + (size_t)b * N_DIM * 512;
        for (int c0 = 0; c0 < 512; c0 += 32) {
            bf16x8 a = *(const bf16x8*)(wa + c0);
            #pragma unroll
            for (int og = 0; og < 4; ++og) {
                bf16x8 xf = *(const bf16x8*)(xb + (size_t)(n0 + og * 16 + lql) * 512 + c0 + lk4 * 8);
                acc[og] = __builtin_amdgcn_mfma_f32_16x16x32_bf16(a, xf, acc[og], 0, 0, 0);
            }
        }
        #pragma unroll
        for (int r = 0; r < 4; ++r) {
            const int c = cb0 + w * 16 + lk4 * 4 + r;
            const float bb = bv[c];
            #pragma unroll
            for (int og = 0; og < 4; ++og) {
                vB[((size_t)(b * C_DIM + c)) * N_DIM + n0 + og * 16 + lql] =
                    f2bf(acc[og][r] + bb);
            }
        }
    }
}

// ---------------------------------------------------------------------------
// flash (MFMA): grid 1024 = {4 b} x {64 m-tiles} x {4 c-quarters}, 256 thr.
// bid%8 = 2b + (ch&1): batch pinned to an XCD pair; V quarter L2-resident.
// 4 blocks/CU (launch_bounds(256,4)) -> 16 waves/CU, 50% occupancy target.
// Block: BM=64 q-rows, c-quarter 128 (wave owns 32 c), KV-tile 64.
// Exports row-0 softmax stats (m,l) from block (mt=0,ch=0) for patch_kernel.
// ---------------------------------------------------------------------------
__global__ __launch_bounds__(256, 4) void flash_kernel(
    const unsigned short* __restrict__ qB,
    const unsigned short* __restrict__ kB,
    const unsigned short* __restrict__ vB,
    const float* __restrict__ x,
    const float* __restrict__ gamma,
    float* __restrict__ stats,
    float* __restrict__ out)
{
    const int bid   = blockIdx.x;
    const int low3  = bid & 7;
    const int b     = low3 >> 1;
    const int c0bit = low3 & 1;
    const int high  = bid >> 3;          // 0..127
    const int mt    = high >> 1;         // 0..63
    const int ch    = ((high & 1) << 1) | c0bit;   // 0..3
    const int m0    = mt * 64;

    const int tid  = threadIdx.x;
    const int w    = tid >> 6;
    const int lane = tid & 63;
    const int lql  = lane & 15;
    const int lk4  = lane >> 4;
    const int swz  = (lql & 7) << 3;

    __shared__ __align__(16) unsigned short Kl[2][4096];
    __shared__ __align__(16) unsigned short Pl[4096];
    __shared__ float scl[64];
    __shared__ float ll[64];
    __shared__ int   fl[4];

    const unsigned short* qrow = qB + ((size_t)b * N_DIM + m0 + w * 16 + lql) * 64 + lk4 * 8;
    const bf16x8 qf0 = *(const bf16x8*)(qrow);
    const bf16x8 qf1 = *(const bf16x8*)(qrow + 32);

    f32x4 acc[2][4];   // [cg][qg]
    #pragma unroll
    for (int cg = 0; cg < 2; ++cg)
        #pragma unroll
        for (int qg = 0; qg < 4; ++qg)
            acc[cg][qg] = (f32x4){0.f, 0.f, 0.f, 0.f};

    float m_run = -3.0e38f;
    float l_run = 0.f;

    const unsigned short* kbb = kB + (size_t)b * N_DIM * 64;
    const unsigned short* vbb = vB + (size_t)b * C_DIM * N_DIM;
    const int cs = ch * 128 + w * 32;

    {
        bf16x8 a0 = *(const bf16x8*)(kbb + tid * 16);
        bf16x8 a1 = *(const bf16x8*)(kbb + tid * 16 + 8);
        *(bf16x8*)(&Kl[0][tid * 16]) = a0;
        *(bf16x8*)(&Kl[0][tid * 16 + 8]) = a1;
    }
    __syncthreads();

    int buf = 0;
    for (int t = 0; t < 64; ++t) {
        const int tn_ = (t + 1) & 63;
        const bf16x8 kn0 = *(const bf16x8*)(kbb + (size_t)tn_ * 4096 + tid * 16);
        const bf16x8 kn1 = *(const bf16x8*)(kbb + (size_t)tn_ * 4096 + tid * 16 + 8);

        // QK^T -> S^T: rows = keys g*16+lk4*4+r, col = qrow = lql
        f32x4 s[4];
        #pragma unroll
        for (int g = 0; g < 4; ++g) {
            const unsigned short* kr = &Kl[buf][(g * 16 + lql) * 64];
            bf16x8 ka0 = *(const bf16x8*)(kr + ((lk4 * 8) ^ swz));
            bf16x8 ka1 = *(const bf16x8*)(kr + ((lk4 * 8 + 32) ^ swz));
            f32x4 z = (f32x4){0.f, 0.f, 0.f, 0.f};
            z = __builtin_amdgcn_mfma_f32_16x16x32_bf16(ka0, qf0, z, 0, 0, 0);
            z = __builtin_amdgcn_mfma_f32_16x16x32_bf16(ka1, qf1, z, 0, 0, 0);
            s[g] = z;
        }

        float pmax = s[0][0];
        #pragma unroll
        for (int g = 0; g < 4; ++g)
            #pragma unroll
            for (int r = 0; r < 4; ++r)
                pmax = fmaxf(pmax, s[g][r]);
        pmax = fmaxf(pmax, __shfl_xor(pmax, 16));
        pmax = fmaxf(pmax, __shfl_xor(pmax, 32));

        const int wflag = __any(pmax > m_run + 8.f);   // defer-max THR=8
        float scv = 1.f;
        if (wflag) {
            const float nm = fmaxf(m_run, pmax);
            scv = __expf(m_run - nm);
            m_run = nm;
        }
        float p[4][4];
        float ps = 0.f;
        #pragma unroll
        for (int g = 0; g < 4; ++g)
            #pragma unroll
            for (int r = 0; r < 4; ++r) {
                p[g][r] = __expf(s[g][r] - m_run);
                ps += p[g][r];
            }
        ps += __shfl_xor(ps, 16);
        ps += __shfl_xor(ps, 32);
        l_run = l_run * scv + ps;

        if (lk4 == 0) scl[w * 16 + lql] = scv;
        if (lane == 0) fl[w] = wflag;

        {
            const int prow = (w * 16 + lql) * 64;
            #pragma unroll
            for (int g = 0; g < 4; ++g) {
                unsigned int lo = (unsigned int)f2bf(p[g][0]) | ((unsigned int)f2bf(p[g][1]) << 16);
                unsigned int hi = (unsigned int)f2bf(p[g][2]) | ((unsigned int)f2bf(p[g][3]) << 16);
                *(uint2*)(&Pl[prow + ((g * 16 + lk4 * 4) ^ swz)]) = make_uint2(lo, hi);
            }
        }
        __syncthreads();

        *(bf16x8*)(&Kl[buf ^ 1][tid * 16]) = kn0;
        *(bf16x8*)(&Kl[buf ^ 1][tid * 16 + 8]) = kn1;

        const int bflag = fl[0] | fl[1] | fl[2] | fl[3];
        if (bflag) {
            float sc4[4];
            #pragma unroll
            for (int qg = 0; qg < 4; ++qg) sc4[qg] = scl[qg * 16 + lql];
            #pragma unroll
            for (int cg = 0; cg < 2; ++cg)
                #pragma unroll
                for (int qg = 0; qg < 4; ++qg) {
                    acc[cg][qg][0] *= sc4[qg];
                    acc[cg][qg][1] *= sc4[qg];
                    acc[cg][qg][2] *= sc4[qg];
                    acc[cg][qg][3] *= sc4[qg];
                }
        }

        bf16x8 pf[4][2];
        #pragma unroll
        for (int qg = 0; qg < 4; ++qg) {
            const unsigned short* pr = &Pl[(qg * 16 + lql) * 64];
            pf[qg][0] = *(const bf16x8*)(pr + ((lk4 * 8) ^ swz));
            pf[qg][1] = *(const bf16x8*)(pr + ((lk4 * 8 + 32) ^ swz));
        }

        const int n0 = t * 64;
        const unsigned short* vpb = vbb + (size_t)(cs + lql) * N_DIM + n0 + lk4 * 8;
        __builtin_amdgcn_s_setprio(1);
        #pragma unroll
        for (int cg = 0; cg < 2; ++cg) {
            const unsigned short* vp = vpb + (size_t)cg * 16 * N_DIM;
            bf16x8 va0 = *(const bf16x8*)(vp);
            bf16x8 va1 = *(const bf16x8*)(vp + 32);
            #pragma unroll
            for (int qg = 0; qg < 4; ++qg) {
                acc[cg][qg] = __builtin_amdgcn_mfma_f32_16x16x32_bf16(va0, pf[qg][0], acc[cg][qg], 0, 0, 0);
                acc[cg][qg] = __builtin_amdgcn_mfma_f32_16x16x32_bf16(va1, pf[qg][1], acc[cg][qg], 0, 0, 0);
            }
        }
        __builtin_amdgcn_s_setprio(0);
        __syncthreads();
        buf ^= 1;
    }

    // export row-0 softmax stats for patch_kernel
    if (mt == 0 && ch == 0 && tid == 0) {
        stats[b * 2 + 0] = m_run;
        stats[b * 2 + 1] = l_run;
    }

    if (lk4 == 0) ll[w * 16 + lql] = l_run;
    __syncthreads();

    const float gns = gamma[0] * NS_F;
    float inv4[4];
    #pragma unroll
    for (int qg = 0; qg < 4; ++qg) inv4[qg] = 1.f / ll[qg * 16 + lql];

    #pragma unroll
    for (int cg = 0; cg < 2; ++cg) {
        #pragma unroll
        for (int r = 0; r < 4; ++r) {
            const int c = cs + cg * 16 + lk4 * 4 + r;
            const size_t rowb = ((size_t)b * C_DIM + c) * N_DIM;
            #pragma unroll
            for (int qg = 0; qg < 4; ++qg) {
                const int mg = m0 + qg * 16 + lql;
                out[rowb + mg] = fmaf(gns * inv4[qg], acc[cg][qg][r], x[rowb + mg]);
            }
        }
    }
}

// ---------------------------------------------------------------------------
// patch: out[b][c][0] -= gamma * (NS * exp(q0.k_s - m)/l) * v[c][s]
// ---------------------------------------------------------------------------
__global__ __launch_bounds__(512) void patch_kernel(
    const unsigned short* __restrict__ qB,
    const unsigned short* __restrict__ kB,
    const unsigned short* __restrict__ vB,
    const float* __restrict__ stats,
    const float* __restrict__ gamma,
    const int* __restrict__ sidx,
    float* __restrict__ out)
{
    const int b = blockIdx.x;
    const int c = threadIdx.x;
    __shared__ float q0s[64];
    if (c < 64) q0s[c] = bf2f(qB[(size_t)b * N_DIM * 64 + c]);
    __syncthreads();
    const int s  = sidx[b];
    const int m7 = s & 7;
    const unsigned short* kr = kB + ((size_t)b * N_DIM + s) * 64;
    float logit = 0.f;
    #pragma unroll
    for (int dj = 0; dj < 8; ++dj) {
        const int slot = dj ^ m7;
        bf16x8 kv = *(const bf16x8*)(kr + slot * 8);
        #pragma unroll
        for (int e = 0; e < 8; ++e)
            logit = fmaf(bf2f((unsigned short)kv[e]), q0s[dj * 8 + e], logit);
    }
    const float corr = NS_F * __expf(logit - stats[b * 2]) / stats[b * 2 + 1];
    const float g = gamma[0];
    const float vcs = bf2f(vB[((size_t)b * C_DIM + c) * N_DIM + s]);
    out[((size_t)b * C_DIM + c) * N_DIM] -= g * corr * vcs;
}

// ---------------------------------------------------------------------------
extern "C" void kernel_launch(void* const* d_in, const int* in_sizes, int n_in,
                              void* d_out, int out_size, void* d_ws, size_t ws_size,
                              hipStream_t stream)
{
    const float* x     = (const float*)d_in[0];
    const float* Wq    = (const float*)d_in[1];
    const float* bq    = (const float*)d_in[2];
    const float* Wk    = (const float*)d_in[3];
    const float* bk    = (const float*)d_in[4];
    const float* Wv    = (const float*)d_in[5];
    const float* bv    = (const float*)d_in[6];
    const float* gamma = (const float*)d_in[7];
    const int*   sidx  = (const int*)d_in[8];
    float* out = (float*)d_out;

    // ws (ushorts): xT 8M | Wb 320K | qB 1M | kB 1M | vB 8M | stats (floats)
    unsigned short* xT = (unsigned short*)d_ws;
    unsigned short* Wb = xT + (size_t)B_DIM * N_DIM * 512;
    unsigned short* qB = Wb + 327680;
    unsigned short* kB = qB + (size_t)B_DIM * N_DIM * 64;
    unsigned short* vB = kB + (size_t)B_DIM * N_DIM * 64;
    float* stats = (float*)(vB + (size_t)B_DIM * C_DIM * N_DIM);

    wconv_kernel<<<dim3(320), 256, 0, stream>>>(Wq, Wk, Wv, Wb);
    xt_kernel<<<dim3(64, 8, B_DIM), 256, 0, stream>>>(x, xT);
    proj_kernel<<<dim3(10, 64, B_DIM), 256, 0, stream>>>(xT, Wb, bq, bk, bv, qB, kB, vB);
    flash_kernel<<<dim3(1024), 256, 0, stream>>>(qB, kB, vB, x, gamma, stats, out);
    patch_kernel<<<dim3(B_DIM), 512, 0, stream>>>(qB, kB, vB, stats, gamma, sidx, out);
}